// Round 13
// baseline (11180.982 us; speedup 1.0000x reference)
//
#include <hip/hip_runtime.h>
#include <cstdint>

typedef __bf16 bf16x8 __attribute__((ext_vector_type(8)));
typedef float  f32x4  __attribute__((ext_vector_type(4)));

union U4B { uint4 u; bf16x8 b; };
__device__ __forceinline__ bf16x8 as_bf(uint4 u) { U4B x; x.u = u; return x.b; }

__device__ __forceinline__ unsigned short f2b(float x) {
  unsigned int u = __float_as_uint(x);
  unsigned int r = (u + 0x7fffu + ((u >> 16) & 1u)) >> 16;
  return (unsigned short)r;
}
__device__ __forceinline__ float b2f(unsigned int bits_lo16) {
  return __uint_as_float(bits_lo16 << 16);
}

__device__ __forceinline__ float sigm(float x) {
  float e = __builtin_amdgcn_exp2f(x * -1.4426950408889634f);
  return __builtin_amdgcn_rcpf(1.0f + e);
}
__device__ __forceinline__ float tanh_fast(float x) {
  float e = __builtin_amdgcn_exp2f(x * 2.8853900817779268f);
  return 1.0f - 2.0f * __builtin_amdgcn_rcpf(e + 1.0f);
}

// ---------------- prep: build permuted bf16 weight layouts in ws ----------------
// recT [1024 col'][256 k]   : col' = 4u+g  <-> orig col = u + 256g
// kb2  [128 ch][1024 col']  : (kernel + bias) same permutation
// dwT  [128 class][256 k]   : dense_w transposed
__global__ void prep_kernel(const float* __restrict__ rec,
                            const float* __restrict__ kern,
                            const float* __restrict__ bias,
                            const float* __restrict__ dw,
                            unsigned short* __restrict__ recT,
                            unsigned short* __restrict__ kb2,
                            unsigned short* __restrict__ dwT) {
  int id = blockIdx.x * 256 + threadIdx.x;
  if (id < 262144) {                       // 1024*256
    int colp = id >> 8, k = id & 255;
    int u = colp >> 2, g = colp & 3;
    recT[colp * 256 + k] = f2b(rec[k * 1024 + u + 256 * g]);
  } else if (id < 262144 + 131072) {       // 128*1024
    int i = id - 262144;
    int ch = i >> 10, colp = i & 1023;
    int u = colp >> 2, g = colp & 3;
    int oc = u + 256 * g;
    kb2[ch * 1024 + colp] = f2b(kern[ch * 1024 + oc] + bias[oc]);
  } else {                                 // 128*256
    int i = id - 262144 - 131072;
    int cls = i >> 8, k = i & 255;
    dwT[cls * 256 + k] = f2b(dw[k * 128 + cls]);
  }
}

// ---------------- DIAGNOSTIC skel2: skeleton + GEMM + gates, NO per-step VMEM ----
// Exactly the R9 step content (16 hf ds_reads, 64 AGPR-operand MFMAs, 8 full
// gate computations, 8 scattered h writes, barrier) but kq loaded once
// pre-loop and no streamed A tiles. compute-cost = skel2/step - 0.40us(skel).
#define SKEL2_STEPS 4096
__global__ __launch_bounds__(512)
__attribute__((amdgpu_waves_per_eu(2, 2)))
void skel2_kernel(const unsigned short* __restrict__ recT,
                  const unsigned short* __restrict__ kb2,
                  float* __restrict__ sink) {
  __shared__ unsigned short h_buf[2][16][264];

  const int tid   = threadIdx.x;
  const int lane  = tid & 63;
  const int wid   = tid >> 6;
  const int row16 = lane & 15;
  const int kg    = lane >> 4;

  const unsigned short* recBase = recT + ((wid * 128 + row16) * 256 + kg * 8);
  uint4 af[4][8];
#pragma unroll
  for (int m = 0; m < 4; ++m)
#pragma unroll
    for (int k = 0; k < 8; ++k) {
      af[m][k] = *(const uint4*)(recBase + m * 4096 + k * 32);
      asm volatile("" : "+a"(af[m][k].x), "+a"(af[m][k].y),
                        "+a"(af[m][k].z), "+a"(af[m][k].w));
    }

  for (int e = tid; e < 16 * 264; e += 512) (&h_buf[0][0][0])[e] = 0;
  for (int e = tid; e < 16 * 264; e += 512) (&h_buf[1][0][0])[e] = 0;

  float c_state[8];
#pragma unroll
  for (int m = 0; m < 8; ++m) c_state[m] = 0.0f;

  // kq loaded ONCE (not per step) — removes per-step VMEM entirely
  uint2 kq0[4], kq1[4];
  {
    const unsigned short* kb = kb2 + (wid * 128 + kg * 4);
#pragma unroll
    for (int m = 0; m < 4; ++m) { kq0[m] = *(const uint2*)(kb + m * 16);
                                  kq1[m] = *(const uint2*)(kb + (4 + m) * 16); }
  }

  __syncthreads();

  int cur = 0;
#pragma unroll 1
  for (int t = 0; t < SKEL2_STEPS; ++t) {
    const unsigned short* hrow = &h_buf[cur][row16][0];
    unsigned short* hn = &h_buf[cur ^ 1][row16][wid * 32 + kg];

    // group A
    {
      f32x4 a0 = {0,0,0,0}, a1 = {0,0,0,0}, a2 = {0,0,0,0}, a3 = {0,0,0,0};
#pragma unroll
      for (int k = 0; k < 8; ++k) {
        uint4 hf = *(const uint4*)(hrow + k * 32 + kg * 8);
        a0 = __builtin_amdgcn_mfma_f32_16x16x32_bf16(as_bf(af[0][k]), as_bf(hf), a0, 0, 0, 0);
        a1 = __builtin_amdgcn_mfma_f32_16x16x32_bf16(as_bf(af[1][k]), as_bf(hf), a1, 0, 0, 0);
        a2 = __builtin_amdgcn_mfma_f32_16x16x32_bf16(as_bf(af[2][k]), as_bf(hf), a2, 0, 0, 0);
        a3 = __builtin_amdgcn_mfma_f32_16x16x32_bf16(as_bf(af[3][k]), as_bf(hf), a3, 0, 0, 0);
      }
      f32x4 ag[4] = {a0, a1, a2, a3};
#pragma unroll
      for (int m = 0; m < 4; ++m) {
        float zi = ag[m][0] + b2f(kq0[m].x & 0xffffu);
        float zf = ag[m][1] + b2f(kq0[m].x >> 16);
        float zg = ag[m][2] + b2f(kq0[m].y & 0xffffu);
        float zo = ag[m][3] + b2f(kq0[m].y >> 16);
        float c  = sigm(zf) * c_state[m] + sigm(zi) * tanh_fast(zg);
        c_state[m] = c;
        hn[m * 4] = f2b(sigm(zo) * tanh_fast(c));
      }
    }
    // group B (af reused as stand-in for m4..7 — timing parity, no VMEM)
    {
      f32x4 b0 = {0,0,0,0}, b1 = {0,0,0,0}, b2v = {0,0,0,0}, b3 = {0,0,0,0};
#pragma unroll
      for (int k = 0; k < 8; ++k) {
        uint4 hf = *(const uint4*)(hrow + k * 32 + kg * 8);
        b0  = __builtin_amdgcn_mfma_f32_16x16x32_bf16(as_bf(af[0][k]), as_bf(hf), b0, 0, 0, 0);
        b1  = __builtin_amdgcn_mfma_f32_16x16x32_bf16(as_bf(af[1][k]), as_bf(hf), b1, 0, 0, 0);
        b2v = __builtin_amdgcn_mfma_f32_16x16x32_bf16(as_bf(af[2][k]), as_bf(hf), b2v, 0, 0, 0);
        b3  = __builtin_amdgcn_mfma_f32_16x16x32_bf16(as_bf(af[3][k]), as_bf(hf), b3, 0, 0, 0);
      }
      f32x4 bg[4] = {b0, b1, b2v, b3};
#pragma unroll
      for (int m = 0; m < 4; ++m) {
        float zi = bg[m][0] + b2f(kq1[m].x & 0xffffu);
        float zf = bg[m][1] + b2f(kq1[m].x >> 16);
        float zg = bg[m][2] + b2f(kq1[m].y & 0xffffu);
        float zo = bg[m][3] + b2f(kq1[m].y >> 16);
        float c  = sigm(zf) * c_state[4 + m] + sigm(zi) * tanh_fast(zg);
        c_state[4 + m] = c;
        hn[(4 + m) * 4] = f2b(sigm(zo) * tanh_fast(c));
      }
    }
    __syncthreads();
    cur ^= 1;
  }

  float s = 0.f;
#pragma unroll
  for (int m = 0; m < 8; ++m) s += c_state[m];
  sink[blockIdx.x * 512 + tid] = s + (float)h_buf[0][row16][lane];
}

// ---------------- real kernel: EXACT R9 (best measured: 2784 us) ----------------
__global__ __launch_bounds__(512)
__attribute__((amdgpu_waves_per_eu(2, 2)))
void lstm_kernel(
    const unsigned short* __restrict__ recT,
    const unsigned short* __restrict__ kb2,
    const unsigned short* __restrict__ dwT,
    const int* __restrict__ x,
    const float* __restrict__ dense_b,
    float* __restrict__ out) {
  __shared__ uint4 A_lds[2][8][512];            // 128 KB, [slot][k][wid*64+lane]
  __shared__ unsigned short h_buf[2][16][264];  // 16.9 KB bf16 h, padded rows

  const int tid   = threadIdx.x;
  const int lane  = tid & 63;
  const int wid   = tid >> 6;      // 0..7
  const int row16 = lane & 15;     // batch row within tile
  const int kg    = lane >> 4;     // 0..3
  const int rbase = blockIdx.x << 4;

  const unsigned short* recBase = recT + ((wid * 128 + row16) * 256 + kg * 8);

  // m0..3 into AGPRs (128 accum regs), loaded once
  uint4 af[4][8];
#pragma unroll
  for (int m = 0; m < 4; ++m)
#pragma unroll
    for (int k = 0; k < 8; ++k) {
      af[m][k] = *(const uint4*)(recBase + m * 4096 + k * 32);
      asm volatile("" : "+a"(af[m][k].x), "+a"(af[m][k].y),
                        "+a"(af[m][k].z), "+a"(af[m][k].w));
    }

  // m4..5 into LDS, staged once
#pragma unroll
  for (int s = 0; s < 2; ++s)
#pragma unroll
    for (int k = 0; k < 8; ++k)
      A_lds[s][k][wid * 64 + lane] = *(const uint4*)(recBase + (4 + s) * 4096 + k * 32);

  // m6..7 stream bases + full 8-frag buffers; preload lo frags 0..3
  const unsigned short* sb6 = recBase + 6 * 4096;
  const unsigned short* sb7 = recBase + 7 * 4096;
  uint4 st6[8], st7[8];
#pragma unroll
  for (int k = 0; k < 4; ++k) {
    st6[k] = *(const uint4*)(sb6 + k * 32);
    st7[k] = *(const uint4*)(sb7 + k * 32);
  }

  // zero h(0)
  for (int e = tid; e < 16 * 264; e += 512) (&h_buf[0][0][0])[e] = 0;

  float c_state[8];
#pragma unroll
  for (int m = 0; m < 8; ++m) c_state[m] = 0.0f;

  const int* xrow = x + (rbase + row16) * 512;
  int idx_cur = xrow[0];
  const int colb = wid * 128;

  // preload kq for t=0
  uint2 kq0[4], kq1[4];
  {
    const unsigned short* kb = kb2 + (idx_cur * 1024 + colb + kg * 4);
#pragma unroll
    for (int m = 0; m < 4; ++m) { kq0[m] = *(const uint2*)(kb + m * 16);
                                  kq1[m] = *(const uint2*)(kb + (4 + m) * 16); }
  }

  __syncthreads();

  int cur = 0;
  const unsigned aoff_base = (wid * 64 + lane) * 16;  // byte off in each [s][k] plane

#pragma unroll 1
  for (int t = 0; t < 512; ++t) {
    unsigned z6 = 0, zL = 0;
    asm volatile("" : "+v"(z6), "+v"(zL));
    const unsigned short* sb6v = sb6 + z6;
    const unsigned short* sb7v = sb7 + z6;
    const unsigned aoff = aoff_base + zL;

    // BURST 1: hi frags 4..7 for THIS step (consumed after group A)
#pragma unroll
    for (int k = 4; k < 8; ++k) {
      st6[k] = *(const uint4*)(sb6v + k * 32);
      st7[k] = *(const uint4*)(sb7v + k * 32);
    }
    int idx_next = xrow[(t + 1 < 512) ? t + 1 : 511];

    const unsigned short* hrow = &h_buf[cur][row16][0];
    unsigned short* hn = &h_buf[cur ^ 1][row16][wid * 32 + kg];

    // ---- group A: m0..3 from AGPRs (no VMEM) ----
    f32x4 a0 = {0,0,0,0}, a1 = {0,0,0,0}, a2 = {0,0,0,0}, a3 = {0,0,0,0};
#pragma unroll
    for (int k = 0; k < 8; ++k) {
      uint4 hf = *(const uint4*)(hrow + k * 32 + kg * 8);
      a0 = __builtin_amdgcn_mfma_f32_16x16x32_bf16(as_bf(af[0][k]), as_bf(hf), a0, 0, 0, 0);
      a1 = __builtin_amdgcn_mfma_f32_16x16x32_bf16(as_bf(af[1][k]), as_bf(hf), a1, 0, 0, 0);
      a2 = __builtin_amdgcn_mfma_f32_16x16x32_bf16(as_bf(af[2][k]), as_bf(hf), a2, 0, 0, 0);
      a3 = __builtin_amdgcn_mfma_f32_16x16x32_bf16(as_bf(af[3][k]), as_bf(hf), a3, 0, 0, 0);
    }
    {
      f32x4 ag[4] = {a0, a1, a2, a3};
#pragma unroll
      for (int m = 0; m < 4; ++m) {
        float zi = ag[m][0] + b2f(kq0[m].x & 0xffffu);
        float zf = ag[m][1] + b2f(kq0[m].x >> 16);
        float zg = ag[m][2] + b2f(kq0[m].y & 0xffffu);
        float zo = ag[m][3] + b2f(kq0[m].y >> 16);
        float c  = sigm(zf) * c_state[m] + sigm(zi) * tanh_fast(zg);
        c_state[m] = c;
        hn[m * 4] = f2b(sigm(zo) * tanh_fast(c));
      }
    }

    // mid: rotate kq0 for t+1
    const unsigned short* kbn = kb2 + (idx_next * 1024 + colb + kg * 4);
#pragma unroll
    for (int m = 0; m < 4; ++m) kq0[m] = *(const uint2*)(kbn + m * 16);

    // ---- group B: m4..5 (LDS) + m6..7 (streamed) ----
    f32x4 b0 = {0,0,0,0}, b1 = {0,0,0,0}, b2v = {0,0,0,0}, b3 = {0,0,0,0};
#pragma unroll
    for (int k = 0; k < 8; ++k) {
      uint4 hf = *(const uint4*)(hrow + k * 32 + kg * 8);
      uint4 a4 = *(const uint4*)((const char*)A_lds + (0 * 8 + k) * 8192 + aoff);
      uint4 a5 = *(const uint4*)((const char*)A_lds + (1 * 8 + k) * 8192 + aoff);
      b0  = __builtin_amdgcn_mfma_f32_16x16x32_bf16(as_bf(a4), as_bf(hf), b0, 0, 0, 0);
      b1  = __builtin_amdgcn_mfma_f32_16x16x32_bf16(as_bf(a5), as_bf(hf), b1, 0, 0, 0);
      b2v = __builtin_amdgcn_mfma_f32_16x16x32_bf16(as_bf(st6[k]), as_bf(hf), b2v, 0, 0, 0);
      b3  = __builtin_amdgcn_mfma_f32_16x16x32_bf16(as_bf(st7[k]), as_bf(hf), b3, 0, 0, 0);
      if (k < 4) {  // reissue lo frag for t+1
        st6[k] = *(const uint4*)(sb6v + k * 32);
        st7[k] = *(const uint4*)(sb7v + k * 32);
      }
    }
    {
      f32x4 bg[4] = {b0, b1, b2v, b3};
#pragma unroll
      for (int m = 0; m < 4; ++m) {
        float zi = bg[m][0] + b2f(kq1[m].x & 0xffffu);
        float zf = bg[m][1] + b2f(kq1[m].x >> 16);
        float zg = bg[m][2] + b2f(kq1[m].y & 0xffffu);
        float zo = bg[m][3] + b2f(kq1[m].y >> 16);
        float c  = sigm(zf) * c_state[4 + m] + sigm(zi) * tanh_fast(zg);
        c_state[4 + m] = c;
        hn[(4 + m) * 4] = f2b(sigm(zo) * tanh_fast(c));
      }
    }

    // rotate kq1 for t+1
#pragma unroll
    for (int m = 0; m < 4; ++m) kq1[m] = *(const uint2*)(kbn + (4 + m) * 16);

    __syncthreads();
    cur ^= 1;
    idx_cur = idx_next;
  }

  // ---- final dense (MFMA) + softmax; final h is in h_buf[0] ----
  float (*l_lds)[132] = (float (*)[132])A_lds;
  {
    const unsigned short* dwBase = dwT + ((wid * 16 + row16) * 256 + kg * 8);
    f32x4 la = {0.f, 0.f, 0.f, 0.f};
#pragma unroll
    for (int k = 0; k < 8; ++k) {
      uint4 hf  = *(const uint4*)&h_buf[0][row16][k * 32 + kg * 8];
      uint4 afd = *(const uint4*)(dwBase + k * 32);
      la = __builtin_amdgcn_mfma_f32_16x16x32_bf16(as_bf(afd), as_bf(hf), la, 0, 0, 0);
    }
#pragma unroll
    for (int r = 0; r < 4; ++r) {
      int cls = wid * 16 + kg * 4 + r;
      l_lds[row16][cls] = la[r] + dense_b[cls];
    }
  }
  __syncthreads();

  {
    int r = tid >> 5, cg = tid & 31;
    float4 v = *(const float4*)&l_lds[r][cg * 4];
    float mx = fmaxf(fmaxf(v.x, v.y), fmaxf(v.z, v.w));
#pragma unroll
    for (int sh = 1; sh < 32; sh <<= 1) mx = fmaxf(mx, __shfl_xor(mx, sh));
    const float L2E = 1.4426950408889634f;
    float e0 = __builtin_amdgcn_exp2f((v.x - mx) * L2E);
    float e1 = __builtin_amdgcn_exp2f((v.y - mx) * L2E);
    float e2 = __builtin_amdgcn_exp2f((v.z - mx) * L2E);
    float e3 = __builtin_amdgcn_exp2f((v.w - mx) * L2E);
    float sm = e0 + e1 + e2 + e3;
#pragma unroll
    for (int sh = 1; sh < 32; sh <<= 1) sm += __shfl_xor(sm, sh);
    float inv = __builtin_amdgcn_rcpf(sm);
    float4 o = {e0 * inv, e1 * inv, e2 * inv, e3 * inv};
    *(float4*)&out[(rbase + r) * 128 + cg * 4] = o;
  }
}

extern "C" void kernel_launch(void* const* d_in, const int* in_sizes, int n_in,
                              void* d_out, int out_size, void* d_ws, size_t ws_size,
                              hipStream_t stream) {
  const int*   x      = (const int*)d_in[0];    // [1024][512] int32
  const float* kern   = (const float*)d_in[1];  // [128][1024]
  const float* rec    = (const float*)d_in[2];  // [256][1024]
  const float* bias   = (const float*)d_in[3];  // [1024]
  const float* dw     = (const float*)d_in[4];  // [256][128]
  const float* db     = (const float*)d_in[5];  // [128]
  float* outp = (float*)d_out;                  // [1024][128]

  unsigned char* ws = (unsigned char*)d_ws;
  unsigned short* recT = (unsigned short*)(ws);            // 512 KB
  unsigned short* kb2  = (unsigned short*)(ws + 524288);   // 256 KB
  unsigned short* dwT  = (unsigned short*)(ws + 786432);   //  64 KB
  float*          sink = (float*)(ws + 851968);            // 128 KB diag sink

  prep_kernel<<<1664, 256, 0, stream>>>(rec, kern, bias, dw, recT, kb2, dwT);
  skel2_kernel<<<64, 512, 0, stream>>>(recT, kb2, sink);
  lstm_kernel<<<64, 512, 0, stream>>>(recT, kb2, dwT, x, db, outp);
}

// Round 14
// 4082.270 us; speedup vs baseline: 2.7389x; 2.7389x over previous
//
#include <hip/hip_runtime.h>
#include <cstdint>

typedef __bf16 bf16x8 __attribute__((ext_vector_type(8)));
typedef float  f32x4  __attribute__((ext_vector_type(4)));

union U4B { uint4 u; bf16x8 b; };
__device__ __forceinline__ bf16x8 as_bf(uint4 u) { U4B x; x.u = u; return x.b; }

__device__ __forceinline__ unsigned short f2b(float x) {
  unsigned int u = __float_as_uint(x);
  unsigned int r = (u + 0x7fffu + ((u >> 16) & 1u)) >> 16;
  return (unsigned short)r;
}
__device__ __forceinline__ float b2f(unsigned int bits_lo16) {
  return __uint_as_float(bits_lo16 << 16);
}

__device__ __forceinline__ float sigm(float x) {
  float e = __builtin_amdgcn_exp2f(x * -1.4426950408889634f);
  return __builtin_amdgcn_rcpf(1.0f + e);
}
__device__ __forceinline__ float tanh_fast(float x) {
  float e = __builtin_amdgcn_exp2f(x * 2.8853900817779268f);
  return 1.0f - 2.0f * __builtin_amdgcn_rcpf(e + 1.0f);
}

// k-permutation (block-packed h layout): physical short position
// s = blk*32 + kg*8 + m  holds unit  u = blk*32 + m*4 + kg.
// So u(s) = (s>>5)*32 + (s&7)*4 + ((s>>3)&3).
__device__ __forceinline__ int kperm_u(int k) {
  return (k & ~31) + (k & 7) * 4 + ((k >> 3) & 3);
}

// ---------------- prep: permuted bf16 weights in ws ----------------
// recT [1024 col'][256 k'] : col' = 4u+g (gate-interleave); k-axis kperm'd
// kb2  [128 ch][1024 col'] : (kernel + bias), col' permutation only
// dwT  [128 class][256 k'] : dense_w transposed, k-axis kperm'd
__global__ void prep_kernel(const float* __restrict__ rec,
                            const float* __restrict__ kern,
                            const float* __restrict__ bias,
                            const float* __restrict__ dw,
                            unsigned short* __restrict__ recT,
                            unsigned short* __restrict__ kb2,
                            unsigned short* __restrict__ dwT) {
  int id = blockIdx.x * 256 + threadIdx.x;
  if (id < 262144) {                       // 1024*256
    int colp = id >> 8, k = id & 255;
    int u = kperm_u(k);
    int oc = (colp >> 2) + 256 * (colp & 3);
    recT[colp * 256 + k] = f2b(rec[u * 1024 + oc]);
  } else if (id < 262144 + 131072) {       // 128*1024
    int i = id - 262144;
    int ch = i >> 10, colp = i & 1023;
    int oc = (colp >> 2) + 256 * (colp & 3);
    kb2[ch * 1024 + colp] = f2b(kern[ch * 1024 + oc] + bias[oc]);
  } else {                                 // 128*256
    int i = id - 262144 - 131072;
    int cls = i >> 8, k = i & 255;
    int u = kperm_u(k);
    dwT[cls * 256 + k] = f2b(dw[u * 128 + cls]);
  }
}

// ---------------- main persistent LSTM kernel ----------------
// R9 tiering (m0..3 AGPR / m4..5 LDS / m6..7 streamed) + two fixes from the
// R12/R13 decomposition:
//  (1) RAW inter-step barrier: s_waitcnt lgkmcnt(0) + s_barrier only. The
//      default __syncthreads drains vmcnt(0), killing all cross-step VMEM
//      prefetch (the measured +3.4 us/step). h_buf only needs LDS ordering.
//  (2) Conflict-balanced h layout: stride 288 shorts (144 dw = 16 mod 32),
//      block-packed k-layout -> hf reads AND the single packed b128 h-write
//      are uniform 8 dwords/bank (minimum possible). No XOR-swizzle ALU.
// All 8 stream frags reissued right after consume -> full-step prefetch
// distance across the raw barrier. kq rotated one step ahead as before.
__global__ __launch_bounds__(512)
__attribute__((amdgpu_waves_per_eu(2, 2)))
void lstm_kernel(
    const unsigned short* __restrict__ recT,
    const unsigned short* __restrict__ kb2,
    const unsigned short* __restrict__ dwT,
    const int* __restrict__ x,
    const float* __restrict__ dense_b,
    float* __restrict__ out) {
  __shared__ uint4 A_lds[2][8][512];            // 128 KB, [slot][k][wid*64+lane]
  __shared__ unsigned short h_buf[2][16][288];  // 18 KB, stride 144 dw == 16 mod 32

  const int tid   = threadIdx.x;
  const int lane  = tid & 63;
  const int wid   = tid >> 6;      // 0..7
  const int row16 = lane & 15;     // batch row within tile
  const int kg    = lane >> 4;     // 0..3
  const int rbase = blockIdx.x << 4;

  const unsigned short* recBase = recT + ((wid * 128 + row16) * 256 + kg * 8);

  // m0..3 into AGPRs (128 accum regs), loaded once
  uint4 af[4][8];
#pragma unroll
  for (int m = 0; m < 4; ++m)
#pragma unroll
    for (int k = 0; k < 8; ++k) {
      af[m][k] = *(const uint4*)(recBase + m * 4096 + k * 32);
      asm volatile("" : "+a"(af[m][k].x), "+a"(af[m][k].y),
                        "+a"(af[m][k].z), "+a"(af[m][k].w));
    }

  // m4..5 into LDS, staged once
#pragma unroll
  for (int s = 0; s < 2; ++s)
#pragma unroll
    for (int k = 0; k < 8; ++k)
      A_lds[s][k][wid * 64 + lane] = *(const uint4*)(recBase + (4 + s) * 4096 + k * 32);

  // m6..7 stream bases; preload all 8 frags
  const unsigned short* sb6 = recBase + 6 * 4096;
  const unsigned short* sb7 = recBase + 7 * 4096;
  uint4 st6[8], st7[8];
#pragma unroll
  for (int k = 0; k < 8; ++k) {
    st6[k] = *(const uint4*)(sb6 + k * 32);
    st7[k] = *(const uint4*)(sb7 + k * 32);
  }

  // zero h(0)
  for (int e = tid; e < 2 * 16 * 288 / 8; e += 512)
    ((uint4*)h_buf)[e] = uint4{0, 0, 0, 0};

  float c_state[8];
#pragma unroll
  for (int m = 0; m < 8; ++m) c_state[m] = 0.0f;

  const int* xrow = x + (rbase + row16) * 512;
  int idx_cur = xrow[0];
  const int colb = wid * 128;

  // preload kq for t=0
  uint2 kq0[4], kq1[4];
  {
    const unsigned short* kb = kb2 + (idx_cur * 1024 + colb + kg * 4);
#pragma unroll
    for (int m = 0; m < 4; ++m) { kq0[m] = *(const uint2*)(kb + m * 16);
                                  kq1[m] = *(const uint2*)(kb + (4 + m) * 16); }
  }

  char* lds = (char*)&h_buf[0][0][0];
  const unsigned rowB  = (unsigned)(row16 * 576);
  const unsigned rdKgo = (unsigned)(kg * 16);                 // read: + k*64
  const unsigned wrOff = rowB + (unsigned)(wid * 64 + kg * 16);
  const unsigned aoff_base = (wid * 64 + lane) * 16;

  __syncthreads();

  int cur = 0;
#pragma unroll 1
  for (int t = 0; t < 512; ++t) {
    unsigned z6 = 0, zL = 0;
    asm volatile("" : "+v"(z6), "+v"(zL));
    const unsigned short* sb6v = sb6 + z6;
    const unsigned short* sb7v = sb7 + z6;
    const unsigned aoff = aoff_base + zL;

    int idx_next = xrow[(t + 1 < 512) ? t + 1 : 511];

    const char* hrdRow = lds + cur * 9216 + rowB;
    unsigned short hb[8];

    // ---- group A: m0..3 from AGPRs (no VMEM) ----
    {
      f32x4 a0 = {0,0,0,0}, a1 = {0,0,0,0}, a2 = {0,0,0,0}, a3 = {0,0,0,0};
#pragma unroll
      for (int k = 0; k < 8; ++k) {
        uint4 hf = *(const uint4*)(hrdRow + k * 64 + rdKgo);
        a0 = __builtin_amdgcn_mfma_f32_16x16x32_bf16(as_bf(af[0][k]), as_bf(hf), a0, 0, 0, 0);
        a1 = __builtin_amdgcn_mfma_f32_16x16x32_bf16(as_bf(af[1][k]), as_bf(hf), a1, 0, 0, 0);
        a2 = __builtin_amdgcn_mfma_f32_16x16x32_bf16(as_bf(af[2][k]), as_bf(hf), a2, 0, 0, 0);
        a3 = __builtin_amdgcn_mfma_f32_16x16x32_bf16(as_bf(af[3][k]), as_bf(hf), a3, 0, 0, 0);
      }
      f32x4 ag[4] = {a0, a1, a2, a3};
#pragma unroll
      for (int m = 0; m < 4; ++m) {
        float zi = ag[m][0] + b2f(kq0[m].x & 0xffffu);
        float zf = ag[m][1] + b2f(kq0[m].x >> 16);
        float zg = ag[m][2] + b2f(kq0[m].y & 0xffffu);
        float zo = ag[m][3] + b2f(kq0[m].y >> 16);
        float c  = sigm(zf) * c_state[m] + sigm(zi) * tanh_fast(zg);
        c_state[m] = c;
        hb[m] = f2b(sigm(zo) * tanh_fast(c));
      }
    }

    // rotate kq0 for t+1 (in flight across the raw barrier)
    const unsigned short* kbn = kb2 + (idx_next * 1024 + colb + kg * 4);
#pragma unroll
    for (int m = 0; m < 4; ++m) kq0[m] = *(const uint2*)(kbn + m * 16);

    // ---- group B: m4..5 (LDS) + m6..7 (streamed regs) ----
    {
      f32x4 b0 = {0,0,0,0}, b1 = {0,0,0,0}, b2v = {0,0,0,0}, b3 = {0,0,0,0};
#pragma unroll
      for (int k = 0; k < 8; ++k) {
        uint4 hf = *(const uint4*)(hrdRow + k * 64 + rdKgo);
        uint4 a4 = *(const uint4*)((const char*)A_lds + (0 * 8 + k) * 8192 + aoff);
        uint4 a5 = *(const uint4*)((const char*)A_lds + (1 * 8 + k) * 8192 + aoff);
        b0  = __builtin_amdgcn_mfma_f32_16x16x32_bf16(as_bf(a4), as_bf(hf), b0, 0, 0, 0);
        b1  = __builtin_amdgcn_mfma_f32_16x16x32_bf16(as_bf(a5), as_bf(hf), b1, 0, 0, 0);
        b2v = __builtin_amdgcn_mfma_f32_16x16x32_bf16(as_bf(st6[k]), as_bf(hf), b2v, 0, 0, 0);
        b3  = __builtin_amdgcn_mfma_f32_16x16x32_bf16(as_bf(st7[k]), as_bf(hf), b3, 0, 0, 0);
        // reissue frag k for t+1 right after consume: ~full-step prefetch
        // distance, and it survives the (raw) barrier.
        st6[k] = *(const uint4*)(sb6v + k * 32);
        st7[k] = *(const uint4*)(sb7v + k * 32);
      }
      f32x4 bg[4] = {b0, b1, b2v, b3};
#pragma unroll
      for (int m = 0; m < 4; ++m) {
        float zi = bg[m][0] + b2f(kq1[m].x & 0xffffu);
        float zf = bg[m][1] + b2f(kq1[m].x >> 16);
        float zg = bg[m][2] + b2f(kq1[m].y & 0xffffu);
        float zo = bg[m][3] + b2f(kq1[m].y >> 16);
        float c  = sigm(zf) * c_state[4 + m] + sigm(zi) * tanh_fast(zg);
        c_state[4 + m] = c;
        hb[4 + m] = f2b(sigm(zo) * tanh_fast(c));
      }
    }

    // rotate kq1 for t+1
#pragma unroll
    for (int m = 0; m < 4; ++m) kq1[m] = *(const uint2*)(kbn + (4 + m) * 16);

    // packed single b128 h-write (block-packed layout, bank-balanced)
    uint4 hwv;
    hwv.x = (unsigned)hb[0] | ((unsigned)hb[1] << 16);
    hwv.y = (unsigned)hb[2] | ((unsigned)hb[3] << 16);
    hwv.z = (unsigned)hb[4] | ((unsigned)hb[5] << 16);
    hwv.w = (unsigned)hb[6] | ((unsigned)hb[7] << 16);
    *(uint4*)(lds + (cur ^ 1) * 9216 + wrOff) = hwv;

    // RAW inter-step barrier: order LDS only; leave VMEM prefetch in flight.
    asm volatile("s_waitcnt lgkmcnt(0)" ::: "memory");
    __builtin_amdgcn_s_barrier();

    cur ^= 1;
    idx_cur = idx_next;
  }

  // ---- final dense (MFMA) + softmax; final h is in buffer 0 (512 even) ----
  float (*l_lds)[132] = (float (*)[132])A_lds;  // overlay logits onto A_lds
  {
    const unsigned short* dwBase = dwT + ((wid * 16 + row16) * 256 + kg * 8);
    f32x4 la = {0.f, 0.f, 0.f, 0.f};
#pragma unroll
    for (int k = 0; k < 8; ++k) {
      uint4 hf  = *(const uint4*)(lds + rowB + k * 64 + rdKgo);
      uint4 afd = *(const uint4*)(dwBase + k * 32);
      la = __builtin_amdgcn_mfma_f32_16x16x32_bf16(as_bf(afd), as_bf(hf), la, 0, 0, 0);
    }
    __syncthreads();  // h_buf reads done before l_lds overlay write
#pragma unroll
    for (int r = 0; r < 4; ++r) {
      int cls = wid * 16 + kg * 4 + r;
      l_lds[row16][cls] = la[r] + dense_b[cls];
    }
  }
  __syncthreads();

  {
    int r = tid >> 5, cg = tid & 31;   // 16 rows x 32 col-groups of 4
    float4 v = *(const float4*)&l_lds[r][cg * 4];
    float mx = fmaxf(fmaxf(v.x, v.y), fmaxf(v.z, v.w));
#pragma unroll
    for (int sh = 1; sh < 32; sh <<= 1) mx = fmaxf(mx, __shfl_xor(mx, sh));
    const float L2E = 1.4426950408889634f;
    float e0 = __builtin_amdgcn_exp2f((v.x - mx) * L2E);
    float e1 = __builtin_amdgcn_exp2f((v.y - mx) * L2E);
    float e2 = __builtin_amdgcn_exp2f((v.z - mx) * L2E);
    float e3 = __builtin_amdgcn_exp2f((v.w - mx) * L2E);
    float sm = e0 + e1 + e2 + e3;
#pragma unroll
    for (int sh = 1; sh < 32; sh <<= 1) sm += __shfl_xor(sm, sh);
    float inv = __builtin_amdgcn_rcpf(sm);
    float4 o = {e0 * inv, e1 * inv, e2 * inv, e3 * inv};
    *(float4*)&out[(rbase + r) * 128 + cg * 4] = o;
  }
}

extern "C" void kernel_launch(void* const* d_in, const int* in_sizes, int n_in,
                              void* d_out, int out_size, void* d_ws, size_t ws_size,
                              hipStream_t stream) {
  const int*   x      = (const int*)d_in[0];    // [1024][512] int32
  const float* kern   = (const float*)d_in[1];  // [128][1024]
  const float* rec    = (const float*)d_in[2];  // [256][1024]
  const float* bias   = (const float*)d_in[3];  // [1024]
  const float* dw     = (const float*)d_in[4];  // [256][128]
  const float* db     = (const float*)d_in[5];  // [128]
  float* outp = (float*)d_out;                  // [1024][128]

  unsigned char* ws = (unsigned char*)d_ws;
  unsigned short* recT = (unsigned short*)(ws);            // 512 KB
  unsigned short* kb2  = (unsigned short*)(ws + 524288);   // 256 KB
  unsigned short* dwT  = (unsigned short*)(ws + 786432);   //  64 KB

  prep_kernel<<<1664, 256, 0, stream>>>(rec, kern, bias, dw, recT, kb2, dwT);
  lstm_kernel<<<64, 512, 0, stream>>>(recT, kb2, dwT, x, db, outp);
}

// Round 15
// 3709.548 us; speedup vs baseline: 3.0141x; 1.1005x over previous
//
#include <hip/hip_runtime.h>
#include <cstdint>

typedef __bf16 bf16x8 __attribute__((ext_vector_type(8)));
typedef float  f32x4  __attribute__((ext_vector_type(4)));

union U4B { uint4 u; bf16x8 b; };
__device__ __forceinline__ bf16x8 as_bf(uint4 u) { U4B x; x.u = u; return x.b; }

// float -> bf16 bits, round-to-nearest-even (finite inputs)
__device__ __forceinline__ unsigned short f2b(float x) {
  unsigned int u = __float_as_uint(x);
  unsigned int r = (u + 0x7fffu + ((u >> 16) & 1u)) >> 16;
  return (unsigned short)r;
}
__device__ __forceinline__ float b2f(unsigned int bits_lo16) {
  return __uint_as_float(bits_lo16 << 16);
}

__device__ __forceinline__ float sigm(float x) {
  float e = __builtin_amdgcn_exp2f(x * -1.4426950408889634f);
  return __builtin_amdgcn_rcpf(1.0f + e);
}
__device__ __forceinline__ float tanh_fast(float x) {
  float e = __builtin_amdgcn_exp2f(x * 2.8853900817779268f);
  return 1.0f - 2.0f * __builtin_amdgcn_rcpf(e + 1.0f);
}

// ---------------- prep: build permuted bf16 weight layouts in ws ----------------
// recT [1024 col'][256 k]   : col' = 4u+g  <-> orig col = u + 256g
// kb2  [128 ch][1024 col']  : (kernel + bias) same permutation
// dwT  [128 class][256 k]   : dense_w transposed
__global__ void prep_kernel(const float* __restrict__ rec,
                            const float* __restrict__ kern,
                            const float* __restrict__ bias,
                            const float* __restrict__ dw,
                            unsigned short* __restrict__ recT,
                            unsigned short* __restrict__ kb2,
                            unsigned short* __restrict__ dwT) {
  int id = blockIdx.x * 256 + threadIdx.x;
  if (id < 262144) {                       // 1024*256
    int colp = id >> 8, k = id & 255;
    int u = colp >> 2, g = colp & 3;
    recT[colp * 256 + k] = f2b(rec[k * 1024 + u + 256 * g]);
  } else if (id < 262144 + 131072) {       // 128*1024
    int i = id - 262144;
    int ch = i >> 10, colp = i & 1023;
    int u = colp >> 2, g = colp & 3;
    int oc = u + 256 * g;
    kb2[ch * 1024 + colp] = f2b(kern[ch * 1024 + oc] + bias[oc]);
  } else {                                 // 128*256
    int i = id - 262144 - 131072;
    int cls = i >> 8, k = i & 255;
    dwT[cls * 256 + k] = f2b(dw[k * 128 + cls]);
  }
}

// ---------------- main persistent LSTM kernel ----------------
// EXACT R9 base (2784 us) with ONE change: step reordered so that streamed
// operands are consumed FIRST (group A) and ALL next-step VMEM (16 stream
// frags + kq rotates) is issued >= ~2000 cycles before __syncthreads.
// R13's decomposition showed the vmcnt(0) drain at the barrier stalling on
// late-issued loads is the prime suspect for the 3.4 us/step VMEM add-on.
//   group A: m4..5 (LDS) + m6..7 (streamed) -> reissue stream -> gates 4..7
//            -> rotate kq1
//   group B: m0..3 (AGPR) -> z-adds (consume kq0) -> rotate kq0 -> trans
//            gates -> h write -> __syncthreads
__global__ __launch_bounds__(512)
__attribute__((amdgpu_waves_per_eu(2, 2)))
void lstm_kernel(
    const unsigned short* __restrict__ recT,
    const unsigned short* __restrict__ kb2,
    const unsigned short* __restrict__ dwT,
    const int* __restrict__ x,
    const float* __restrict__ dense_b,
    float* __restrict__ out) {
  __shared__ uint4 A_lds[2][8][512];            // 128 KB, [slot][k][wid*64+lane]
  __shared__ unsigned short h_buf[2][16][264];  // 16.9 KB bf16 h, padded rows

  const int tid   = threadIdx.x;
  const int lane  = tid & 63;
  const int wid   = tid >> 6;      // 0..7
  const int row16 = lane & 15;     // batch row within tile
  const int kg    = lane >> 4;     // 0..3
  const int rbase = blockIdx.x << 4;

  const unsigned short* recBase = recT + ((wid * 128 + row16) * 256 + kg * 8);

  // m0..3 into AGPRs (128 accum regs), loaded once
  uint4 af[4][8];
#pragma unroll
  for (int m = 0; m < 4; ++m)
#pragma unroll
    for (int k = 0; k < 8; ++k) {
      af[m][k] = *(const uint4*)(recBase + m * 4096 + k * 32);
      asm volatile("" : "+a"(af[m][k].x), "+a"(af[m][k].y),
                        "+a"(af[m][k].z), "+a"(af[m][k].w));
    }

  // m4..5 into LDS, staged once
#pragma unroll
  for (int s = 0; s < 2; ++s)
#pragma unroll
    for (int k = 0; k < 8; ++k)
      A_lds[s][k][wid * 64 + lane] = *(const uint4*)(recBase + (4 + s) * 4096 + k * 32);

  // m6..7 stream bases; preload ALL 8 frags (consumed first thing in step 0)
  const unsigned short* sb6 = recBase + 6 * 4096;
  const unsigned short* sb7 = recBase + 7 * 4096;
  uint4 st6[8], st7[8];
#pragma unroll
  for (int k = 0; k < 8; ++k) {
    st6[k] = *(const uint4*)(sb6 + k * 32);
    st7[k] = *(const uint4*)(sb7 + k * 32);
  }

  // zero h(0)
  for (int e = tid; e < 16 * 264; e += 512) (&h_buf[0][0][0])[e] = 0;

  float c_state[8];
#pragma unroll
  for (int m = 0; m < 8; ++m) c_state[m] = 0.0f;

  const int* xrow = x + (rbase + row16) * 512;
  int idx_cur = xrow[0];
  const int colb = wid * 128;

  // preload kq for t=0
  uint2 kq0[4], kq1[4];
  {
    const unsigned short* kb = kb2 + (idx_cur * 1024 + colb + kg * 4);
#pragma unroll
    for (int m = 0; m < 4; ++m) { kq0[m] = *(const uint2*)(kb + m * 16);
                                  kq1[m] = *(const uint2*)(kb + (4 + m) * 16); }
  }

  __syncthreads();

  int cur = 0;
  const unsigned aoff_base = (wid * 64 + lane) * 16;  // byte off in each [s][k] plane

#pragma unroll 1
  for (int t = 0; t < 512; ++t) {
    unsigned z6 = 0, zL = 0;
    asm volatile("" : "+v"(z6), "+v"(zL));
    const unsigned short* sb6v = sb6 + z6;
    const unsigned short* sb7v = sb7 + z6;
    const unsigned aoff = aoff_base + zL;

    int idx_next = xrow[(t + 1 < 512) ? t + 1 : 511];

    const unsigned short* hrow = &h_buf[cur][row16][0];
    unsigned short* hn = &h_buf[cur ^ 1][row16][wid * 32 + kg];

    // ---- group A: m4..5 (LDS) + m6..7 (streamed, loaded LAST step) ----
    f32x4 b0 = {0,0,0,0}, b1 = {0,0,0,0}, b2v = {0,0,0,0}, b3 = {0,0,0,0};
#pragma unroll
    for (int k = 0; k < 8; ++k) {
      uint4 hf = *(const uint4*)(hrow + k * 32 + kg * 8);
      uint4 a4 = *(const uint4*)((const char*)A_lds + (0 * 8 + k) * 8192 + aoff);
      uint4 a5 = *(const uint4*)((const char*)A_lds + (1 * 8 + k) * 8192 + aoff);
      b0  = __builtin_amdgcn_mfma_f32_16x16x32_bf16(as_bf(a4), as_bf(hf), b0, 0, 0, 0);
      b1  = __builtin_amdgcn_mfma_f32_16x16x32_bf16(as_bf(a5), as_bf(hf), b1, 0, 0, 0);
      b2v = __builtin_amdgcn_mfma_f32_16x16x32_bf16(as_bf(st6[k]), as_bf(hf), b2v, 0, 0, 0);
      b3  = __builtin_amdgcn_mfma_f32_16x16x32_bf16(as_bf(st7[k]), as_bf(hf), b3, 0, 0, 0);
    }

    // reissue ALL 16 stream frags for t+1 NOW (~2000 cyc before the barrier)
#pragma unroll
    for (int k = 0; k < 8; ++k) {
      st6[k] = *(const uint4*)(sb6v + k * 32);
      st7[k] = *(const uint4*)(sb7v + k * 32);
    }

    // gates for units 4..7 (consume kq1), then rotate kq1 for t+1
    {
      f32x4 bg[4] = {b0, b1, b2v, b3};
#pragma unroll
      for (int m = 0; m < 4; ++m) {
        float zi = bg[m][0] + b2f(kq1[m].x & 0xffffu);
        float zf = bg[m][1] + b2f(kq1[m].x >> 16);
        float zg = bg[m][2] + b2f(kq1[m].y & 0xffffu);
        float zo = bg[m][3] + b2f(kq1[m].y >> 16);
        float c  = sigm(zf) * c_state[4 + m] + sigm(zi) * tanh_fast(zg);
        c_state[4 + m] = c;
        hn[(4 + m) * 4] = f2b(sigm(zo) * tanh_fast(c));
      }
    }
    const unsigned short* kbn = kb2 + (idx_next * 1024 + colb + kg * 4);
#pragma unroll
    for (int m = 0; m < 4; ++m) kq1[m] = *(const uint2*)(kbn + (4 + m) * 16);

    // ---- group B: m0..3 from AGPRs (no VMEM) ----
    f32x4 a0 = {0,0,0,0}, a1 = {0,0,0,0}, a2 = {0,0,0,0}, a3 = {0,0,0,0};
#pragma unroll
    for (int k = 0; k < 8; ++k) {
      uint4 hf = *(const uint4*)(hrow + k * 32 + kg * 8);
      a0 = __builtin_amdgcn_mfma_f32_16x16x32_bf16(as_bf(af[0][k]), as_bf(hf), a0, 0, 0, 0);
      a1 = __builtin_amdgcn_mfma_f32_16x16x32_bf16(as_bf(af[1][k]), as_bf(hf), a1, 0, 0, 0);
      a2 = __builtin_amdgcn_mfma_f32_16x16x32_bf16(as_bf(af[2][k]), as_bf(hf), a2, 0, 0, 0);
      a3 = __builtin_amdgcn_mfma_f32_16x16x32_bf16(as_bf(af[3][k]), as_bf(hf), a3, 0, 0, 0);
    }
    {
      f32x4 ag[4] = {a0, a1, a2, a3};
      float zi[4], zf[4], zg[4], zo[4];
      // consume kq0 into z first...
#pragma unroll
      for (int m = 0; m < 4; ++m) {
        zi[m] = ag[m][0] + b2f(kq0[m].x & 0xffffu);
        zf[m] = ag[m][1] + b2f(kq0[m].x >> 16);
        zg[m] = ag[m][2] + b2f(kq0[m].y & 0xffffu);
        zo[m] = ag[m][3] + b2f(kq0[m].y >> 16);
      }
      // ...then rotate kq0 (still ~600 cyc of trans math before the barrier)
#pragma unroll
      for (int m = 0; m < 4; ++m) kq0[m] = *(const uint2*)(kbn + m * 16);
      // transcendental phase
#pragma unroll
      for (int m = 0; m < 4; ++m) {
        float c = sigm(zf[m]) * c_state[m] + sigm(zi[m]) * tanh_fast(zg[m]);
        c_state[m] = c;
        hn[m * 4] = f2b(sigm(zo[m]) * tanh_fast(c));
      }
    }

    __syncthreads();
    cur ^= 1;
    idx_cur = idx_next;
  }

  // ---- final dense (MFMA) + softmax; final h is in h_buf[0] ----
  float (*l_lds)[132] = (float (*)[132])A_lds;
  {
    const unsigned short* dwBase = dwT + ((wid * 16 + row16) * 256 + kg * 8);
    f32x4 la = {0.f, 0.f, 0.f, 0.f};
#pragma unroll
    for (int k = 0; k < 8; ++k) {
      uint4 hf  = *(const uint4*)&h_buf[0][row16][k * 32 + kg * 8];
      uint4 afd = *(const uint4*)(dwBase + k * 32);
      la = __builtin_amdgcn_mfma_f32_16x16x32_bf16(as_bf(afd), as_bf(hf), la, 0, 0, 0);
    }
#pragma unroll
    for (int r = 0; r < 4; ++r) {
      int cls = wid * 16 + kg * 4 + r;
      l_lds[row16][cls] = la[r] + dense_b[cls];
    }
  }
  __syncthreads();

  {
    int r = tid >> 5, cg = tid & 31;
    float4 v = *(const float4*)&l_lds[r][cg * 4];
    float mx = fmaxf(fmaxf(v.x, v.y), fmaxf(v.z, v.w));
#pragma unroll
    for (int sh = 1; sh < 32; sh <<= 1) mx = fmaxf(mx, __shfl_xor(mx, sh));
    const float L2E = 1.4426950408889634f;
    float e0 = __builtin_amdgcn_exp2f((v.x - mx) * L2E);
    float e1 = __builtin_amdgcn_exp2f((v.y - mx) * L2E);
    float e2 = __builtin_amdgcn_exp2f((v.z - mx) * L2E);
    float e3 = __builtin_amdgcn_exp2f((v.w - mx) * L2E);
    float sm = e0 + e1 + e2 + e3;
#pragma unroll
    for (int sh = 1; sh < 32; sh <<= 1) sm += __shfl_xor(sm, sh);
    float inv = __builtin_amdgcn_rcpf(sm);
    float4 o = {e0 * inv, e1 * inv, e2 * inv, e3 * inv};
    *(float4*)&out[(rbase + r) * 128 + cg * 4] = o;
  }
}

extern "C" void kernel_launch(void* const* d_in, const int* in_sizes, int n_in,
                              void* d_out, int out_size, void* d_ws, size_t ws_size,
                              hipStream_t stream) {
  const int*   x      = (const int*)d_in[0];    // [1024][512] int32
  const float* kern   = (const float*)d_in[1];  // [128][1024]
  const float* rec    = (const float*)d_in[2];  // [256][1024]
  const float* bias   = (const float*)d_in[3];  // [1024]
  const float* dw     = (const float*)d_in[4];  // [256][128]
  const float* db     = (const float*)d_in[5];  // [128]
  float* outp = (float*)d_out;                  // [1024][128]

  unsigned char* ws = (unsigned char*)d_ws;
  unsigned short* recT = (unsigned short*)(ws);            // 512 KB
  unsigned short* kb2  = (unsigned short*)(ws + 524288);   // 256 KB
  unsigned short* dwT  = (unsigned short*)(ws + 786432);   //  64 KB

  prep_kernel<<<1664, 256, 0, stream>>>(rec, kern, bias, dw, recT, kb2, dwT);
  lstm_kernel<<<64, 512, 0, stream>>>(recT, kb2, dwT, x, db, outp);
}

// Round 16
// 3289.341 us; speedup vs baseline: 3.3992x; 1.1277x over previous
//
#include <hip/hip_runtime.h>
#include <cstdint>

typedef __bf16 bf16x8 __attribute__((ext_vector_type(8)));
typedef float  f32x4  __attribute__((ext_vector_type(4)));

union U4B { uint4 u; bf16x8 b; };
__device__ __forceinline__ bf16x8 as_bf(uint4 u) { U4B x; x.u = u; return x.b; }

// float -> bf16 bits, round-to-nearest-even (finite inputs)
__device__ __forceinline__ unsigned short f2b(float x) {
  unsigned int u = __float_as_uint(x);
  unsigned int r = (u + 0x7fffu + ((u >> 16) & 1u)) >> 16;
  return (unsigned short)r;
}
__device__ __forceinline__ float b2f(unsigned int bits_lo16) {
  return __uint_as_float(bits_lo16 << 16);
}

__device__ __forceinline__ float sigm(float x) {
  float e = __builtin_amdgcn_exp2f(x * -1.4426950408889634f);
  return __builtin_amdgcn_rcpf(1.0f + e);
}
__device__ __forceinline__ float tanh_fast(float x) {
  float e = __builtin_amdgcn_exp2f(x * 2.8853900817779268f);
  return 1.0f - 2.0f * __builtin_amdgcn_rcpf(e + 1.0f);
}

// ---------------- prep: build permuted bf16 weight layouts in ws ----------------
// recT [1024 col'][256 k]   : col' = 4u+g  <-> orig col = u + 256g
// kb2  [128 ch][1024 col']  : (kernel + bias) same permutation
// dwT  [128 class][256 k]   : dense_w transposed
__global__ void prep_kernel(const float* __restrict__ rec,
                            const float* __restrict__ kern,
                            const float* __restrict__ bias,
                            const float* __restrict__ dw,
                            unsigned short* __restrict__ recT,
                            unsigned short* __restrict__ kb2,
                            unsigned short* __restrict__ dwT) {
  int id = blockIdx.x * 256 + threadIdx.x;
  if (id < 262144) {                       // 1024*256
    int colp = id >> 8, k = id & 255;
    int u = colp >> 2, g = colp & 3;
    recT[colp * 256 + k] = f2b(rec[k * 1024 + u + 256 * g]);
  } else if (id < 262144 + 131072) {       // 128*1024
    int i = id - 262144;
    int ch = i >> 10, colp = i & 1023;
    int u = colp >> 2, g = colp & 3;
    int oc = u + 256 * g;
    kb2[ch * 1024 + colp] = f2b(kern[ch * 1024 + oc] + bias[oc]);
  } else {                                 // 128*256
    int i = id - 262144 - 131072;
    int cls = i >> 8, k = i & 255;
    dwT[cls * 256 + k] = f2b(dw[k * 128 + cls]);
  }
}

// ---------------- main persistent LSTM kernel ----------------
// R9 base with ONE mechanism change: the kq gather (16 scattered kb2 rows per
// wave-instruction — the prime suspect for the +3.4us/step VMEM cost) is
// replaced by a COOPERATIVE COALESCED load: wave w streams kb2 rows for batch
// rows 2w,2w+1 as contiguous 2KB bursts into a double-buffered kq_lds; gates
// read kq from LDS. idx is pre-held one step ahead (scalar), loads issue at
// step top, ds_writes land after group A (latency hidden under MFMA).
// A tiers: m0..3 AGPR (R9-proven) | m4 LDS (64 KB) | m5..7 streamed window-2.
__global__ __launch_bounds__(512)
__attribute__((amdgpu_waves_per_eu(2, 2)))
void lstm_kernel(
    const unsigned short* __restrict__ recT,
    const unsigned short* __restrict__ kb2,
    const unsigned short* __restrict__ dwT,
    const int* __restrict__ x,
    const float* __restrict__ dense_b,
    float* __restrict__ out) {
  __shared__ uint4 A_lds[8][512];                 // 64 KB (m4): [k][wid*64+lane]
  __shared__ unsigned short kq_lds[2][16][1032];  // 66 KB dbuf; 516dw row ≡4 mod 32
  __shared__ unsigned short h_buf[2][16][264];    // 16.9 KB (R9 layout)

  const int tid   = threadIdx.x;
  const int lane  = tid & 63;
  const int wid   = tid >> 6;      // 0..7
  const int row16 = lane & 15;     // batch row within tile
  const int kg    = lane >> 4;     // 0..3
  const int rbase = blockIdx.x << 4;

  const unsigned short* recBase = recT + ((wid * 128 + row16) * 256 + kg * 8);

  // m0..3 into AGPRs (128 accum regs), loaded once
  uint4 af[4][8];
#pragma unroll
  for (int m = 0; m < 4; ++m)
#pragma unroll
    for (int k = 0; k < 8; ++k) {
      af[m][k] = *(const uint4*)(recBase + m * 4096 + k * 32);
      asm volatile("" : "+a"(af[m][k].x), "+a"(af[m][k].y),
                        "+a"(af[m][k].z), "+a"(af[m][k].w));
    }

  // m4 into LDS, staged once
#pragma unroll
  for (int k = 0; k < 8; ++k)
    A_lds[k][wid * 64 + lane] = *(const uint4*)(recBase + 4 * 4096 + k * 32);

  // m5..7 stream bases; window-2 (slot = k&1; 2|8 keeps phase aligned)
  const unsigned short* sb5 = recBase + 5 * 4096;
  const unsigned short* sb6 = recBase + 6 * 4096;
  const unsigned short* sb7 = recBase + 7 * 4096;
  uint4 st5[2], st6[2], st7[2];
#pragma unroll
  for (int k = 0; k < 2; ++k) {
    st5[k] = *(const uint4*)(sb5 + k * 32);
    st6[k] = *(const uint4*)(sb6 + k * 32);
    st7[k] = *(const uint4*)(sb7 + k * 32);
  }

  // zero h(0)
  for (int e = tid; e < 16 * 264; e += 512) (&h_buf[0][0][0])[e] = 0;

  float c_state[8];
#pragma unroll
  for (int m = 0; m < 8; ++m) c_state[m] = 0.0f;

  // cooperative kq preload for t=0 (wave w owns batch rows 2w, 2w+1)
  const int r0 = 2 * wid, r1 = 2 * wid + 1;
  {
    int ia0 = x[(rbase + r0) * 512 + 0];
    int ia1 = x[(rbase + r1) * 512 + 0];
    const unsigned short* s0 = kb2 + ia0 * 1024;
    const unsigned short* s1 = kb2 + ia1 * 1024;
    uint4 a = *(const uint4*)(s0 + lane * 8);
    uint4 b = *(const uint4*)(s0 + 512 + lane * 8);
    uint4 c = *(const uint4*)(s1 + lane * 8);
    uint4 d = *(const uint4*)(s1 + 512 + lane * 8);
    *(uint4*)((char*)&kq_lds[0][r0][0] + lane * 16) = a;
    *(uint4*)((char*)&kq_lds[0][r0][0] + 1024 + lane * 16) = b;
    *(uint4*)((char*)&kq_lds[0][r1][0] + lane * 16) = c;
    *(uint4*)((char*)&kq_lds[0][r1][0] + 1024 + lane * 16) = d;
  }
  // idx for t=1 (used at step 0 to issue kq(1)); scalar (wave-uniform)
  int ib0 = x[(rbase + r0) * 512 + 1];
  int ib1 = x[(rbase + r1) * 512 + 1];

  __syncthreads();

  int cur = 0;
  const unsigned aoff_base = (wid * 64 + lane) * 16;

#pragma unroll 1
  for (int t = 0; t < 512; ++t) {
    unsigned z6 = 0, zL = 0;
    asm volatile("" : "+v"(z6), "+v"(zL));
    const unsigned short* sb5v = sb5 + z6;
    const unsigned short* sb6v = sb6 + z6;
    const unsigned short* sb7v = sb7 + z6;
    const unsigned aoff = aoff_base + zL;

    // 1) issue coalesced kq(t+1) loads (idx pre-held); consumed mid-step as writes
    const unsigned short* s0 = kb2 + ib0 * 1024;
    const unsigned short* s1 = kb2 + ib1 * 1024;
    uint4 q0 = *(const uint4*)(s0 + lane * 8);
    uint4 q1 = *(const uint4*)(s0 + 512 + lane * 8);
    uint4 q2 = *(const uint4*)(s1 + lane * 8);
    uint4 q3 = *(const uint4*)(s1 + 512 + lane * 8);
    // idx for t+2
    int tn2 = (t + 2 < 512) ? t + 2 : 511;
    ib0 = x[(rbase + r0) * 512 + tn2];
    ib1 = x[(rbase + r1) * 512 + tn2];

    const unsigned short* hrow  = &h_buf[cur][row16][0];
    unsigned short*       hn    = &h_buf[cur ^ 1][row16][wid * 32 + kg];
    const unsigned short* kqrow = &kq_lds[cur][row16][wid * 128 + kg * 4];

    // ---- group A: m0..3 from AGPRs ----
    {
      f32x4 a0 = {0,0,0,0}, a1 = {0,0,0,0}, a2 = {0,0,0,0}, a3 = {0,0,0,0};
#pragma unroll
      for (int k = 0; k < 8; ++k) {
        uint4 hf = *(const uint4*)(hrow + k * 32 + kg * 8);
        a0 = __builtin_amdgcn_mfma_f32_16x16x32_bf16(as_bf(af[0][k]), as_bf(hf), a0, 0, 0, 0);
        a1 = __builtin_amdgcn_mfma_f32_16x16x32_bf16(as_bf(af[1][k]), as_bf(hf), a1, 0, 0, 0);
        a2 = __builtin_amdgcn_mfma_f32_16x16x32_bf16(as_bf(af[2][k]), as_bf(hf), a2, 0, 0, 0);
        a3 = __builtin_amdgcn_mfma_f32_16x16x32_bf16(as_bf(af[3][k]), as_bf(hf), a3, 0, 0, 0);
      }
      f32x4 ag[4] = {a0, a1, a2, a3};
#pragma unroll
      for (int m = 0; m < 4; ++m) {
        uint2 kq = *(const uint2*)(kqrow + m * 16);
        float zi = ag[m][0] + b2f(kq.x & 0xffffu);
        float zf = ag[m][1] + b2f(kq.x >> 16);
        float zg = ag[m][2] + b2f(kq.y & 0xffffu);
        float zo = ag[m][3] + b2f(kq.y >> 16);
        float c  = sigm(zf) * c_state[m] + sigm(zi) * tanh_fast(zg);
        c_state[m] = c;
        hn[m * 4] = f2b(sigm(zo) * tanh_fast(c));
      }
    }

    // 2) land kq(t+1) into the other buffer (loads have had ~2000 cyc)
    {
      char* qd0 = (char*)&kq_lds[cur ^ 1][r0][0];
      char* qd1 = (char*)&kq_lds[cur ^ 1][r1][0];
      *(uint4*)(qd0 + lane * 16) = q0;
      *(uint4*)(qd0 + 1024 + lane * 16) = q1;
      *(uint4*)(qd1 + lane * 16) = q2;
      *(uint4*)(qd1 + 1024 + lane * 16) = q3;
    }

    // ---- group B: m4 (LDS) + m5..7 (streamed, window-2) ----
    {
      f32x4 b0 = {0,0,0,0}, b1 = {0,0,0,0}, b2v = {0,0,0,0}, b3 = {0,0,0,0};
#pragma unroll
      for (int k = 0; k < 8; ++k) {
        uint4 hf = *(const uint4*)(hrow + k * 32 + kg * 8);
        uint4 a4 = *(const uint4*)((const char*)A_lds + k * 8192 + aoff);
        b0  = __builtin_amdgcn_mfma_f32_16x16x32_bf16(as_bf(a4), as_bf(hf), b0, 0, 0, 0);
        b1  = __builtin_amdgcn_mfma_f32_16x16x32_bf16(as_bf(st5[k & 1]), as_bf(hf), b1, 0, 0, 0);
        b2v = __builtin_amdgcn_mfma_f32_16x16x32_bf16(as_bf(st6[k & 1]), as_bf(hf), b2v, 0, 0, 0);
        b3  = __builtin_amdgcn_mfma_f32_16x16x32_bf16(as_bf(st7[k & 1]), as_bf(hf), b3, 0, 0, 0);
        const int kp = (k + 2) & 7;   // window-2 prefetch (time-invariant A)
        st5[k & 1] = *(const uint4*)(sb5v + kp * 32);
        st6[k & 1] = *(const uint4*)(sb6v + kp * 32);
        st7[k & 1] = *(const uint4*)(sb7v + kp * 32);
      }
      f32x4 bg[4] = {b0, b1, b2v, b3};
#pragma unroll
      for (int m = 0; m < 4; ++m) {
        uint2 kq = *(const uint2*)(kqrow + (4 + m) * 16);
        float zi = bg[m][0] + b2f(kq.x & 0xffffu);
        float zf = bg[m][1] + b2f(kq.x >> 16);
        float zg = bg[m][2] + b2f(kq.y & 0xffffu);
        float zo = bg[m][3] + b2f(kq.y >> 16);
        float c  = sigm(zf) * c_state[4 + m] + sigm(zi) * tanh_fast(zg);
        c_state[4 + m] = c;
        hn[(4 + m) * 4] = f2b(sigm(zo) * tanh_fast(c));
      }
    }

    __syncthreads();
    cur ^= 1;
  }

  // ---- final dense (MFMA) + softmax; final h is in h_buf[0] (512 even) ----
  float (*l_lds)[132] = (float (*)[132])A_lds;  // overlay logits onto A_lds
  {
    const unsigned short* dwBase = dwT + ((wid * 16 + row16) * 256 + kg * 8);
    f32x4 la = {0.f, 0.f, 0.f, 0.f};
#pragma unroll
    for (int k = 0; k < 8; ++k) {
      uint4 hf  = *(const uint4*)&h_buf[0][row16][k * 32 + kg * 8];
      uint4 afd = *(const uint4*)(dwBase + k * 32);
      la = __builtin_amdgcn_mfma_f32_16x16x32_bf16(as_bf(afd), as_bf(hf), la, 0, 0, 0);
    }
    __syncthreads();  // everyone done with A_lds-region reads before overlay
#pragma unroll
    for (int r = 0; r < 4; ++r) {
      int cls = wid * 16 + kg * 4 + r;
      l_lds[row16][cls] = la[r] + dense_b[cls];
    }
  }
  __syncthreads();

  {
    int r = tid >> 5, cg = tid & 31;   // 16 rows x 32 col-groups of 4
    float4 v = *(const float4*)&l_lds[r][cg * 4];
    float mx = fmaxf(fmaxf(v.x, v.y), fmaxf(v.z, v.w));
#pragma unroll
    for (int sh = 1; sh < 32; sh <<= 1) mx = fmaxf(mx, __shfl_xor(mx, sh));
    const float L2E = 1.4426950408889634f;
    float e0 = __builtin_amdgcn_exp2f((v.x - mx) * L2E);
    float e1 = __builtin_amdgcn_exp2f((v.y - mx) * L2E);
    float e2 = __builtin_amdgcn_exp2f((v.z - mx) * L2E);
    float e3 = __builtin_amdgcn_exp2f((v.w - mx) * L2E);
    float sm = e0 + e1 + e2 + e3;
#pragma unroll
    for (int sh = 1; sh < 32; sh <<= 1) sm += __shfl_xor(sm, sh);
    float inv = __builtin_amdgcn_rcpf(sm);
    float4 o = {e0 * inv, e1 * inv, e2 * inv, e3 * inv};
    *(float4*)&out[(rbase + r) * 128 + cg * 4] = o;
  }
}

extern "C" void kernel_launch(void* const* d_in, const int* in_sizes, int n_in,
                              void* d_out, int out_size, void* d_ws, size_t ws_size,
                              hipStream_t stream) {
  const int*   x      = (const int*)d_in[0];    // [1024][512] int32
  const float* kern   = (const float*)d_in[1];  // [128][1024]
  const float* rec    = (const float*)d_in[2];  // [256][1024]
  const float* bias   = (const float*)d_in[3];  // [1024]
  const float* dw     = (const float*)d_in[4];  // [256][128]
  const float* db     = (const float*)d_in[5];  // [128]
  float* outp = (float*)d_out;                  // [1024][128]

  unsigned char* ws = (unsigned char*)d_ws;
  unsigned short* recT = (unsigned short*)(ws);            // 512 KB
  unsigned short* kb2  = (unsigned short*)(ws + 524288);   // 256 KB
  unsigned short* dwT  = (unsigned short*)(ws + 786432);   //  64 KB

  prep_kernel<<<1664, 256, 0, stream>>>(rec, kern, bias, dw, recT, kb2, dwT);
  lstm_kernel<<<64, 512, 0, stream>>>(recT, kb2, dwT, x, db, outp);
}